// Round 14
// baseline (381.186 us; speedup 1.0000x reference)
//
#include <hip/hip_runtime.h>
#include <hip/hip_cooperative_groups.h>

namespace cg = cooperative_groups;

#define D_FEAT 32
#define BNODES 32             // nodes per coarse bucket
#define LOG_BN 5
#define NB_MAX 3200           // max buckets (N=100000 -> 3125)
#define CHUNK 8192            // edges per build chunk (8 per thread at 1024 thr)
#define CAP 2048              // fixed packed slots per bucket (mean load 512)
#define CMASK 0x1FFFFu        // low 17 bits = col
#define GRID_BLKS 256         // persistent blocks (1 per CU)

__global__ void __launch_bounds__(1024) fused_kernel_v2(const float* __restrict__ x,
                                                        const int* __restrict__ row,
                                                        const int* __restrict__ col,
                                                        int* __restrict__ cnt,
                                                        unsigned* __restrict__ packed,
                                                        float* __restrict__ out,
                                                        int E, int N, int nb, int nchunks) {
    __shared__ int histA[NB_MAX];          // 12.8 KB (phase A)
    __shared__ int baseA[NB_MAX];          // 12.8 KB (phase A)
    __shared__ unsigned scol[4][CAP];      // 32 KB   (phase B)
    __shared__ int hist2[4][BNODES];
    __shared__ int hoff2[4][BNODES];

    cg::grid_group grid = cg::this_grid();
    int t = threadIdx.x;
    int blk = blockIdx.x;

    // ---------- phase 0: zero per-bucket counters ----------
    for (int i = blk * 1024 + t; i < nb; i += gridDim.x * 1024) cnt[i] = 0;
    __threadfence();
    grid.sync();

    // ---------- phase A: build (blocks 0..nchunks-1 each own one chunk) ----------
    if (blk < nchunks) {
        for (int i = t; i < nb; i += 1024) histA[i] = 0;

        int s = blk * CHUNK;
        int e_end = min(E, s + CHUNK);
        int e0 = s + t * 4;
        int e1 = e0 + 4096;

        int4 r0, c0, r1, c1;
        if (s + CHUNK <= E) {
            r0 = *(const int4*)&row[e0];
            c0 = *(const int4*)&col[e0];
            r1 = *(const int4*)&row[e1];
            c1 = *(const int4*)&col[e1];
        } else {
            r0.x = (e0 + 0 < e_end) ? row[e0 + 0] : -1;
            r0.y = (e0 + 1 < e_end) ? row[e0 + 1] : -1;
            r0.z = (e0 + 2 < e_end) ? row[e0 + 2] : -1;
            r0.w = (e0 + 3 < e_end) ? row[e0 + 3] : -1;
            c0.x = (e0 + 0 < e_end) ? col[e0 + 0] : 0;
            c0.y = (e0 + 1 < e_end) ? col[e0 + 1] : 0;
            c0.z = (e0 + 2 < e_end) ? col[e0 + 2] : 0;
            c0.w = (e0 + 3 < e_end) ? col[e0 + 3] : 0;
            r1.x = (e1 + 0 < e_end) ? row[e1 + 0] : -1;
            r1.y = (e1 + 1 < e_end) ? row[e1 + 1] : -1;
            r1.z = (e1 + 2 < e_end) ? row[e1 + 2] : -1;
            r1.w = (e1 + 3 < e_end) ? row[e1 + 3] : -1;
            c1.x = (e1 + 0 < e_end) ? col[e1 + 0] : 0;
            c1.y = (e1 + 1 < e_end) ? col[e1 + 1] : 0;
            c1.z = (e1 + 2 < e_end) ? col[e1 + 2] : 0;
            c1.w = (e1 + 3 < e_end) ? col[e1 + 3] : 0;
        }
        __syncthreads();  // histA zeroed

        if (r0.x >= 0) atomicAdd(&histA[r0.x >> LOG_BN], 1);
        if (r0.y >= 0) atomicAdd(&histA[r0.y >> LOG_BN], 1);
        if (r0.z >= 0) atomicAdd(&histA[r0.z >> LOG_BN], 1);
        if (r0.w >= 0) atomicAdd(&histA[r0.w >> LOG_BN], 1);
        if (r1.x >= 0) atomicAdd(&histA[r1.x >> LOG_BN], 1);
        if (r1.y >= 0) atomicAdd(&histA[r1.y >> LOG_BN], 1);
        if (r1.z >= 0) atomicAdd(&histA[r1.z >> LOG_BN], 1);
        if (r1.w >= 0) atomicAdd(&histA[r1.w >> LOG_BN], 1);
        __syncthreads();

        for (int i = t; i < nb; i += 1024) {
            int h = histA[i];
            baseA[i] = h ? (i * CAP + atomicAdd(&cnt[i], h)) : 0;
        }
        __syncthreads();

        #define EMIT(rr, cc)                                                  \
            if ((rr) >= 0) {                                                  \
                int b_ = (rr) >> LOG_BN;                                      \
                int slot_ = baseA[b_] + atomicAdd(&histA[b_], -1) - 1;        \
                packed[slot_] = ((unsigned)((rr) & (BNODES - 1)) << 17) |     \
                                (unsigned)(cc);                               \
            }
        EMIT(r0.x, c0.x); EMIT(r0.y, c0.y); EMIT(r0.z, c0.z); EMIT(r0.w, c0.w);
        EMIT(r1.x, c1.x); EMIT(r1.y, c1.y); EMIT(r1.z, c1.z); EMIT(r1.w, c1.w);
        #undef EMIT
    }
    __threadfence();
    grid.sync();
    __threadfence();

    // ---------- phase B: per-bucket sort + register reduce (4 groups of 256) ----------
    int sub = t >> 8;        // bucket group 0..3
    int tt = t & 255;        // thread within group
    int node = tt >> 3;      // node 0..31
    int j = tt & 7;          // float4 quad 0..7
    const float4* x4 = (const float4*)x;
    int P = gridDim.x * 4;
    int trips = (nb + P - 1) / P;

    for (int k = 0; k < trips; ++k) {
        int vb = k * P + blk * 4 + sub;
        int n = (vb < nb) ? cnt[vb] : 0;
        int s = vb * CAP;

        if (tt < BNODES) hist2[sub][tt] = 0;
        __syncthreads();
        for (int i = tt; i < n; i += 256)
            atomicAdd(&hist2[sub][packed[s + i] >> 17], 1);
        __syncthreads();
        if (tt < 64) {
            int v = (tt < BNODES) ? hist2[sub][tt] : 0;
            int sum = v;
            #pragma unroll
            for (int off = 1; off < BNODES; off <<= 1) {
                int w = __shfl_up(sum, off);
                if (tt >= off) sum += w;
            }
            if (tt < BNODES) hoff2[sub][tt] = sum - v;
        }
        __syncthreads();
        int mcount = hist2[sub][node];
        int mbase = hoff2[sub][node];
        __syncthreads();
        for (int i = tt; i < n; i += 256) {
            unsigned p = packed[s + i];
            int r = p >> 17;
            int slot = hoff2[sub][r] + atomicAdd(&hist2[sub][r], -1) - 1;
            scol[sub][slot] = p;
        }
        __syncthreads();

        float4 acc = make_float4(0.f, 0.f, 0.f, 0.f);
        int i = 0;
        for (; i + 3 < mcount; i += 4) {
            unsigned cc0 = scol[sub][mbase + i + 0] & CMASK;
            unsigned cc1 = scol[sub][mbase + i + 1] & CMASK;
            unsigned cc2 = scol[sub][mbase + i + 2] & CMASK;
            unsigned cc3 = scol[sub][mbase + i + 3] & CMASK;
            float4 v0 = x4[cc0 * 8 + j];
            float4 v1 = x4[cc1 * 8 + j];
            float4 v2 = x4[cc2 * 8 + j];
            float4 v3 = x4[cc3 * 8 + j];
            acc.x += v0.x; acc.y += v0.y; acc.z += v0.z; acc.w += v0.w;
            acc.x += v1.x; acc.y += v1.y; acc.z += v1.z; acc.w += v1.w;
            acc.x += v2.x; acc.y += v2.y; acc.z += v2.z; acc.w += v2.w;
            acc.x += v3.x; acc.y += v3.y; acc.z += v3.z; acc.w += v3.w;
        }
        for (; i < mcount; ++i) {
            unsigned cc = scol[sub][mbase + i] & CMASK;
            float4 v = x4[cc * 8 + j];
            acc.x += v.x; acc.y += v.y; acc.z += v.z; acc.w += v.w;
        }

        if (vb < nb) {
            int gnode = vb * BNODES + node;
            if (gnode < N) {
                float invd = 1.0f / fmaxf((float)mcount, 1.0f);
                float4 v;
                v.x = acc.x * invd; v.y = acc.y * invd;
                v.z = acc.z * invd; v.w = acc.w * invd;
                ((float4*)out)[(size_t)gnode * 8 + j] = v;
            }
        }
        __syncthreads();  // scol/hist reused next trip
    }
}

// ---------------- launch ----------------

extern "C" void kernel_launch(void* const* d_in, const int* in_sizes, int n_in,
                              void* d_out, int out_size, void* d_ws, size_t ws_size,
                              hipStream_t stream) {
    const float* x = (const float*)d_in[0];
    const int* edge_index = (const int*)d_in[1];

    int E = in_sizes[1] / 2;
    const int* row = edge_index;      // edge_index[0]
    const int* col = edge_index + E;  // edge_index[1]
    int N = in_sizes[0] / D_FEAT;

    float* out = (float*)d_out;

    int nb = (N + BNODES - 1) / BNODES;     // 3125 buckets
    int nchunks = (E + CHUNK - 1) / CHUNK;  // 196

    // ws layout (ints): cnt[nb] (64-aligned pad) | packed[nb*CAP]
    int* cnt = (int*)d_ws;
    unsigned* packed = (unsigned*)(cnt + ((nb + 63) & ~63));

    void* args[] = {(void*)&x, (void*)&row, (void*)&col, (void*)&cnt,
                    (void*)&packed, (void*)&out, (void*)&E, (void*)&N,
                    (void*)&nb, (void*)&nchunks};
    (void)hipLaunchCooperativeKernel((void*)fused_kernel_v2, dim3(GRID_BLKS),
                                     dim3(1024), args, 0, stream);
}

// Round 15
// 66.934 us; speedup vs baseline: 5.6950x; 5.6950x over previous
//
#include <hip/hip_runtime.h>

#define D_FEAT 32
#define BNODES 32             // nodes per coarse bucket
#define LOG_BN 5
#define CHUNK 4096            // edges per build block (4 per thread at 1024 thr)
#define BIG 1024              // threads for build kernel
#define ECHUNK 1024           // edges per in-block sort chunk (phase 2)
#define CAP 2048              // fixed packed slots per bucket (mean load 512)
#define CMASK 0x1FFFFu        // low 17 bits = col

// ---- zero per-bucket fill counters ----
__global__ void zero_kernel(int* __restrict__ p, int n) {
    int i = blockIdx.x * blockDim.x + threadIdx.x;
    if (i < n) p[i] = 0;
}

// ---- single-pass build: stage 4 edges/thread in regs, LDS hist,
//      reserve fixed-CAP region per bucket, emit packed ----
__global__ void __launch_bounds__(BIG) build_kernel(const int* __restrict__ row,
                                                    const int* __restrict__ col,
                                                    int* __restrict__ cnt,
                                                    unsigned* __restrict__ packed,
                                                    int E, int nb) {
    extern __shared__ int shmem[];
    int* hist = shmem;       // nb: per-chunk histogram, then countdown
    int* base = shmem + nb;  // nb: global slot base for this (chunk,bucket)
    int t = threadIdx.x;
    int blk = blockIdx.x;
    for (int i = t; i < nb; i += BIG) hist[i] = 0;

    int s = blk * CHUNK;
    int e_end = min(E, s + CHUNK);
    int e0 = s + t * 4;

    int4 r0, c0;
    if (s + CHUNK <= E) {
        r0 = *(const int4*)&row[e0];
        c0 = *(const int4*)&col[e0];
    } else {
        r0.x = (e0 + 0 < e_end) ? row[e0 + 0] : -1;
        r0.y = (e0 + 1 < e_end) ? row[e0 + 1] : -1;
        r0.z = (e0 + 2 < e_end) ? row[e0 + 2] : -1;
        r0.w = (e0 + 3 < e_end) ? row[e0 + 3] : -1;
        c0.x = (e0 + 0 < e_end) ? col[e0 + 0] : 0;
        c0.y = (e0 + 1 < e_end) ? col[e0 + 1] : 0;
        c0.z = (e0 + 2 < e_end) ? col[e0 + 2] : 0;
        c0.w = (e0 + 3 < e_end) ? col[e0 + 3] : 0;
    }
    __syncthreads();  // hist zeroed

    if (r0.x >= 0) atomicAdd(&hist[r0.x >> LOG_BN], 1);
    if (r0.y >= 0) atomicAdd(&hist[r0.y >> LOG_BN], 1);
    if (r0.z >= 0) atomicAdd(&hist[r0.z >> LOG_BN], 1);
    if (r0.w >= 0) atomicAdd(&hist[r0.w >> LOG_BN], 1);
    __syncthreads();

    // reserve: one global atomic per (chunk,bucket) with nonzero count
    for (int i = t; i < nb; i += BIG) {
        int h = hist[i];
        base[i] = h ? (i * CAP + atomicAdd(&cnt[i], h)) : 0;
    }
    __syncthreads();

    #define EMIT(rr, cc)                                                      \
        if ((rr) >= 0) {                                                      \
            int b_ = (rr) >> LOG_BN;                                          \
            int slot_ = base[b_] + atomicAdd(&hist[b_], -1) - 1;              \
            packed[slot_] = ((unsigned)((rr) & (BNODES - 1)) << 17) |         \
                            (unsigned)(cc);                                   \
        }
    EMIT(r0.x, c0.x); EMIT(r0.y, c0.y); EMIT(r0.z, c0.z); EMIT(r0.w, c0.w);
    #undef EMIT
}

// ---- phase 2: in-block counting sort + register-accumulated reduce (8-deep) ----
__global__ void __launch_bounds__(256) phase2_kernel(const float* __restrict__ x,
                                                     const unsigned* __restrict__ packed,
                                                     const int* __restrict__ cnt,
                                                     float* __restrict__ out, int N) {
    __shared__ unsigned scol[ECHUNK];   // 4 KB: row-sorted packed entries
    __shared__ int hist[BNODES];
    __shared__ int hoff[BNODES];
    int t = threadIdx.x;
    int b = blockIdx.x;
    int s = b * CAP;
    int n = cnt[b];
    int node = t >> 3;
    int j = t & 7;
    const float4* x4 = (const float4*)x;

    float4 acc = make_float4(0.f, 0.f, 0.f, 0.f);
    int mydeg = 0;

    for (int cs = 0; cs < n; cs += ECHUNK) {
        int m = min(ECHUNK, n - cs);
        if (t < BNODES) hist[t] = 0;
        __syncthreads();
        for (int i = t; i < m; i += 256)
            atomicAdd(&hist[packed[s + cs + i] >> 17], 1);
        __syncthreads();
        if (t < 64) {
            int v = (t < BNODES) ? hist[t] : 0;
            int sum = v;
            #pragma unroll
            for (int off = 1; off < BNODES; off <<= 1) {
                int w = __shfl_up(sum, off);
                if (t >= off) sum += w;
            }
            if (t < BNODES) hoff[t] = sum - v;
        }
        __syncthreads();
        int mcount = hist[node];
        int mbase = hoff[node];
        mydeg += mcount;
        __syncthreads();
        for (int i = t; i < m; i += 256) {
            unsigned p = packed[s + cs + i];
            int r = p >> 17;
            int slot = hoff[r] + atomicAdd(&hist[r], -1) - 1;
            scol[slot] = p;
        }
        __syncthreads();

        // 8 independent float4 gathers in flight
        int i = 0;
        for (; i + 7 < mcount; i += 8) {
            unsigned cc0 = scol[mbase + i + 0] & CMASK;
            unsigned cc1 = scol[mbase + i + 1] & CMASK;
            unsigned cc2 = scol[mbase + i + 2] & CMASK;
            unsigned cc3 = scol[mbase + i + 3] & CMASK;
            unsigned cc4 = scol[mbase + i + 4] & CMASK;
            unsigned cc5 = scol[mbase + i + 5] & CMASK;
            unsigned cc6 = scol[mbase + i + 6] & CMASK;
            unsigned cc7 = scol[mbase + i + 7] & CMASK;
            float4 v0 = x4[cc0 * 8 + j];
            float4 v1 = x4[cc1 * 8 + j];
            float4 v2 = x4[cc2 * 8 + j];
            float4 v3 = x4[cc3 * 8 + j];
            float4 v4 = x4[cc4 * 8 + j];
            float4 v5 = x4[cc5 * 8 + j];
            float4 v6 = x4[cc6 * 8 + j];
            float4 v7 = x4[cc7 * 8 + j];
            acc.x += v0.x; acc.y += v0.y; acc.z += v0.z; acc.w += v0.w;
            acc.x += v1.x; acc.y += v1.y; acc.z += v1.z; acc.w += v1.w;
            acc.x += v2.x; acc.y += v2.y; acc.z += v2.z; acc.w += v2.w;
            acc.x += v3.x; acc.y += v3.y; acc.z += v3.z; acc.w += v3.w;
            acc.x += v4.x; acc.y += v4.y; acc.z += v4.z; acc.w += v4.w;
            acc.x += v5.x; acc.y += v5.y; acc.z += v5.z; acc.w += v5.w;
            acc.x += v6.x; acc.y += v6.y; acc.z += v6.z; acc.w += v6.w;
            acc.x += v7.x; acc.y += v7.y; acc.z += v7.z; acc.w += v7.w;
        }
        for (; i < mcount; ++i) {
            unsigned cc = scol[mbase + i] & CMASK;
            float4 v = x4[cc * 8 + j];
            acc.x += v.x; acc.y += v.y; acc.z += v.z; acc.w += v.w;
        }
        __syncthreads();
    }

    int gnode = b * BNODES + node;
    if (gnode < N) {
        float invd = 1.0f / fmaxf((float)mydeg, 1.0f);
        float4 v;
        v.x = acc.x * invd; v.y = acc.y * invd;
        v.z = acc.z * invd; v.w = acc.w * invd;
        ((float4*)out)[(size_t)gnode * 8 + j] = v;
    }
}

// ---------------- launch ----------------

extern "C" void kernel_launch(void* const* d_in, const int* in_sizes, int n_in,
                              void* d_out, int out_size, void* d_ws, size_t ws_size,
                              hipStream_t stream) {
    const float* x = (const float*)d_in[0];
    const int* edge_index = (const int*)d_in[1];

    int E = in_sizes[1] / 2;
    const int* row = edge_index;      // edge_index[0]
    const int* col = edge_index + E;  // edge_index[1]
    int N = in_sizes[0] / D_FEAT;

    float* out = (float*)d_out;

    int nb = (N + BNODES - 1) / BNODES;     // 3125 buckets
    int nchunks = (E + CHUNK - 1) / CHUNK;  // 391

    // ws layout (ints): cnt[nb] (64-aligned pad) | packed[nb*CAP]  (~25.6 MB)
    int* cnt = (int*)d_ws;
    unsigned* packed = (unsigned*)(cnt + ((nb + 63) & ~63));

    zero_kernel<<<(nb + 255) / 256, 256, 0, stream>>>(cnt, nb);

    size_t lds = (size_t)2 * nb * sizeof(int);
    build_kernel<<<nchunks, BIG, lds, stream>>>(row, col, cnt, packed, E, nb);
    phase2_kernel<<<nb, 256, 0, stream>>>(x, packed, cnt, out, N);
}

// Round 16
// 58.387 us; speedup vs baseline: 6.5286x; 1.1464x over previous
//
#include <hip/hip_runtime.h>

#define D_FEAT 32
#define BNODES 32             // nodes per coarse bucket
#define LOG_BN 5
#define CHUNK 8192            // edges per build block (8 per thread at 1024 thr)
#define BIG 1024              // threads for build kernel
#define ECHUNK 1024           // edges per in-block sort chunk (phase 2)
#define CAP 2048              // fixed packed slots per bucket (mean load 512)
#define CMASK 0x1FFFFu        // low 17 bits = col

// ---- zero per-bucket fill counters ----
__global__ void zero_kernel(int* __restrict__ p, int n) {
    int i = blockIdx.x * blockDim.x + threadIdx.x;
    if (i < n) p[i] = 0;
}

// ---- single-pass build: stage 8 edges/thread in regs, LDS hist,
//      reserve fixed-CAP region per bucket, emit packed ----
__global__ void __launch_bounds__(BIG) build_kernel(const int* __restrict__ row,
                                                    const int* __restrict__ col,
                                                    int* __restrict__ cnt,
                                                    unsigned* __restrict__ packed,
                                                    int E, int nb) {
    extern __shared__ int shmem[];
    int* hist = shmem;       // nb: per-chunk histogram, then countdown
    int* base = shmem + nb;  // nb: global slot base for this (chunk,bucket)
    int t = threadIdx.x;
    int blk = blockIdx.x;
    for (int i = t; i < nb; i += BIG) hist[i] = 0;

    int s = blk * CHUNK;
    int e_end = min(E, s + CHUNK);
    int e0 = s + t * 4;
    int e1 = e0 + BIG * 4;

    int4 r0, c0, r1, c1;
    if (s + CHUNK <= E) {
        r0 = *(const int4*)&row[e0];
        c0 = *(const int4*)&col[e0];
        r1 = *(const int4*)&row[e1];
        c1 = *(const int4*)&col[e1];
    } else {
        r0.x = (e0 + 0 < e_end) ? row[e0 + 0] : -1;
        r0.y = (e0 + 1 < e_end) ? row[e0 + 1] : -1;
        r0.z = (e0 + 2 < e_end) ? row[e0 + 2] : -1;
        r0.w = (e0 + 3 < e_end) ? row[e0 + 3] : -1;
        c0.x = (e0 + 0 < e_end) ? col[e0 + 0] : 0;
        c0.y = (e0 + 1 < e_end) ? col[e0 + 1] : 0;
        c0.z = (e0 + 2 < e_end) ? col[e0 + 2] : 0;
        c0.w = (e0 + 3 < e_end) ? col[e0 + 3] : 0;
        r1.x = (e1 + 0 < e_end) ? row[e1 + 0] : -1;
        r1.y = (e1 + 1 < e_end) ? row[e1 + 1] : -1;
        r1.z = (e1 + 2 < e_end) ? row[e1 + 2] : -1;
        r1.w = (e1 + 3 < e_end) ? row[e1 + 3] : -1;
        c1.x = (e1 + 0 < e_end) ? col[e1 + 0] : 0;
        c1.y = (e1 + 1 < e_end) ? col[e1 + 1] : 0;
        c1.z = (e1 + 2 < e_end) ? col[e1 + 2] : 0;
        c1.w = (e1 + 3 < e_end) ? col[e1 + 3] : 0;
    }
    __syncthreads();  // hist zeroed

    if (r0.x >= 0) atomicAdd(&hist[r0.x >> LOG_BN], 1);
    if (r0.y >= 0) atomicAdd(&hist[r0.y >> LOG_BN], 1);
    if (r0.z >= 0) atomicAdd(&hist[r0.z >> LOG_BN], 1);
    if (r0.w >= 0) atomicAdd(&hist[r0.w >> LOG_BN], 1);
    if (r1.x >= 0) atomicAdd(&hist[r1.x >> LOG_BN], 1);
    if (r1.y >= 0) atomicAdd(&hist[r1.y >> LOG_BN], 1);
    if (r1.z >= 0) atomicAdd(&hist[r1.z >> LOG_BN], 1);
    if (r1.w >= 0) atomicAdd(&hist[r1.w >> LOG_BN], 1);
    __syncthreads();

    // reserve fixed-capacity region slots: one global atomic per (chunk,bucket)
    for (int i = t; i < nb; i += BIG) {
        int h = hist[i];
        base[i] = h ? (i * CAP + atomicAdd(&cnt[i], h)) : 0;
    }
    __syncthreads();

    #define EMIT(rr, cc)                                                      \
        if ((rr) >= 0) {                                                      \
            int b_ = (rr) >> LOG_BN;                                          \
            int slot_ = base[b_] + atomicAdd(&hist[b_], -1) - 1;              \
            packed[slot_] = ((unsigned)((rr) & (BNODES - 1)) << 17) |         \
                            (unsigned)(cc);                                   \
        }
    EMIT(r0.x, c0.x); EMIT(r0.y, c0.y); EMIT(r0.z, c0.z); EMIT(r0.w, c0.w);
    EMIT(r1.x, c1.x); EMIT(r1.y, c1.y); EMIT(r1.z, c1.z); EMIT(r1.w, c1.w);
    #undef EMIT
}

// ---- phase 2: in-block counting sort + register-accumulated reduce (8-deep) ----
__global__ void __launch_bounds__(256) phase2_kernel(const float* __restrict__ x,
                                                     const unsigned* __restrict__ packed,
                                                     const int* __restrict__ cnt,
                                                     float* __restrict__ out, int N) {
    __shared__ unsigned scol[ECHUNK];   // 4 KB: row-sorted packed entries
    __shared__ int hist[BNODES];
    __shared__ int hoff[BNODES];
    int t = threadIdx.x;
    int b = blockIdx.x;
    int s = b * CAP;
    int n = cnt[b];
    int node = t >> 3;
    int j = t & 7;
    const float4* x4 = (const float4*)x;

    float4 acc = make_float4(0.f, 0.f, 0.f, 0.f);
    int mydeg = 0;

    for (int cs = 0; cs < n; cs += ECHUNK) {
        int m = min(ECHUNK, n - cs);
        if (t < BNODES) hist[t] = 0;
        __syncthreads();
        for (int i = t; i < m; i += 256)
            atomicAdd(&hist[packed[s + cs + i] >> 17], 1);
        __syncthreads();
        if (t < 64) {
            int v = (t < BNODES) ? hist[t] : 0;
            int sum = v;
            #pragma unroll
            for (int off = 1; off < BNODES; off <<= 1) {
                int w = __shfl_up(sum, off);
                if (t >= off) sum += w;
            }
            if (t < BNODES) hoff[t] = sum - v;
        }
        __syncthreads();
        int mcount = hist[node];
        int mbase = hoff[node];
        mydeg += mcount;
        __syncthreads();
        for (int i = t; i < m; i += 256) {
            unsigned p = packed[s + cs + i];
            int r = p >> 17;
            int slot = hoff[r] + atomicAdd(&hist[r], -1) - 1;
            scol[slot] = p;
        }
        __syncthreads();

        // 8 independent float4 gathers in flight
        int i = 0;
        for (; i + 7 < mcount; i += 8) {
            unsigned cc0 = scol[mbase + i + 0] & CMASK;
            unsigned cc1 = scol[mbase + i + 1] & CMASK;
            unsigned cc2 = scol[mbase + i + 2] & CMASK;
            unsigned cc3 = scol[mbase + i + 3] & CMASK;
            unsigned cc4 = scol[mbase + i + 4] & CMASK;
            unsigned cc5 = scol[mbase + i + 5] & CMASK;
            unsigned cc6 = scol[mbase + i + 6] & CMASK;
            unsigned cc7 = scol[mbase + i + 7] & CMASK;
            float4 v0 = x4[cc0 * 8 + j];
            float4 v1 = x4[cc1 * 8 + j];
            float4 v2 = x4[cc2 * 8 + j];
            float4 v3 = x4[cc3 * 8 + j];
            float4 v4 = x4[cc4 * 8 + j];
            float4 v5 = x4[cc5 * 8 + j];
            float4 v6 = x4[cc6 * 8 + j];
            float4 v7 = x4[cc7 * 8 + j];
            acc.x += v0.x; acc.y += v0.y; acc.z += v0.z; acc.w += v0.w;
            acc.x += v1.x; acc.y += v1.y; acc.z += v1.z; acc.w += v1.w;
            acc.x += v2.x; acc.y += v2.y; acc.z += v2.z; acc.w += v2.w;
            acc.x += v3.x; acc.y += v3.y; acc.z += v3.z; acc.w += v3.w;
            acc.x += v4.x; acc.y += v4.y; acc.z += v4.z; acc.w += v4.w;
            acc.x += v5.x; acc.y += v5.y; acc.z += v5.z; acc.w += v5.w;
            acc.x += v6.x; acc.y += v6.y; acc.z += v6.z; acc.w += v6.w;
            acc.x += v7.x; acc.y += v7.y; acc.z += v7.z; acc.w += v7.w;
        }
        for (; i < mcount; ++i) {
            unsigned cc = scol[mbase + i] & CMASK;
            float4 v = x4[cc * 8 + j];
            acc.x += v.x; acc.y += v.y; acc.z += v.z; acc.w += v.w;
        }
        __syncthreads();
    }

    int gnode = b * BNODES + node;
    if (gnode < N) {
        float invd = 1.0f / fmaxf((float)mydeg, 1.0f);
        float4 v;
        v.x = acc.x * invd; v.y = acc.y * invd;
        v.z = acc.z * invd; v.w = acc.w * invd;
        ((float4*)out)[(size_t)gnode * 8 + j] = v;
    }
}

// ---------------- launch ----------------

extern "C" void kernel_launch(void* const* d_in, const int* in_sizes, int n_in,
                              void* d_out, int out_size, void* d_ws, size_t ws_size,
                              hipStream_t stream) {
    const float* x = (const float*)d_in[0];
    const int* edge_index = (const int*)d_in[1];

    int E = in_sizes[1] / 2;
    const int* row = edge_index;      // edge_index[0]
    const int* col = edge_index + E;  // edge_index[1]
    int N = in_sizes[0] / D_FEAT;

    float* out = (float*)d_out;

    int nb = (N + BNODES - 1) / BNODES;     // 3125 buckets
    int nchunks = (E + CHUNK - 1) / CHUNK;  // 196

    // ws layout (ints): cnt[nb] (64-aligned pad) | packed[nb*CAP]  (~25.6 MB)
    int* cnt = (int*)d_ws;
    unsigned* packed = (unsigned*)(cnt + ((nb + 63) & ~63));

    zero_kernel<<<(nb + 255) / 256, 256, 0, stream>>>(cnt, nb);

    size_t lds = (size_t)2 * nb * sizeof(int);
    build_kernel<<<nchunks, BIG, lds, stream>>>(row, col, cnt, packed, E, nb);
    phase2_kernel<<<nb, 256, 0, stream>>>(x, packed, cnt, out, N);
}

// Round 17
// 57.674 us; speedup vs baseline: 6.6093x; 1.0124x over previous
//
#include <hip/hip_runtime.h>

#define D_FEAT 32
#define BNODES 64             // nodes per coarse bucket
#define LOG_BN 6
#define CHUNK 8192            // edges per build block (8 per thread at 1024 thr)
#define BIG 1024              // threads for build kernel
#define ECHUNK 2048           // edges per in-block sort chunk (phase 2)
#define CAP 2048              // fixed packed slots per bucket (mean load 1024)
#define CMASK 0x1FFFFu        // low 17 bits = col

// ---- zero per-bucket fill counters ----
__global__ void zero_kernel(int* __restrict__ p, int n) {
    int i = blockIdx.x * blockDim.x + threadIdx.x;
    if (i < n) p[i] = 0;
}

// ---- single-pass build: stage 8 edges/thread in regs, LDS hist,
//      reserve fixed-CAP region per bucket, emit packed ----
__global__ void __launch_bounds__(BIG) build_kernel(const int* __restrict__ row,
                                                    const int* __restrict__ col,
                                                    int* __restrict__ cnt,
                                                    unsigned* __restrict__ packed,
                                                    int E, int nb) {
    extern __shared__ int shmem[];
    int* hist = shmem;       // nb: per-chunk histogram, then countdown
    int* base = shmem + nb;  // nb: global slot base for this (chunk,bucket)
    int t = threadIdx.x;
    int blk = blockIdx.x;
    for (int i = t; i < nb; i += BIG) hist[i] = 0;

    int s = blk * CHUNK;
    int e_end = min(E, s + CHUNK);
    int e0 = s + t * 4;
    int e1 = e0 + BIG * 4;

    int4 r0, c0, r1, c1;
    if (s + CHUNK <= E) {
        r0 = *(const int4*)&row[e0];
        c0 = *(const int4*)&col[e0];
        r1 = *(const int4*)&row[e1];
        c1 = *(const int4*)&col[e1];
    } else {
        r0.x = (e0 + 0 < e_end) ? row[e0 + 0] : -1;
        r0.y = (e0 + 1 < e_end) ? row[e0 + 1] : -1;
        r0.z = (e0 + 2 < e_end) ? row[e0 + 2] : -1;
        r0.w = (e0 + 3 < e_end) ? row[e0 + 3] : -1;
        c0.x = (e0 + 0 < e_end) ? col[e0 + 0] : 0;
        c0.y = (e0 + 1 < e_end) ? col[e0 + 1] : 0;
        c0.z = (e0 + 2 < e_end) ? col[e0 + 2] : 0;
        c0.w = (e0 + 3 < e_end) ? col[e0 + 3] : 0;
        r1.x = (e1 + 0 < e_end) ? row[e1 + 0] : -1;
        r1.y = (e1 + 1 < e_end) ? row[e1 + 1] : -1;
        r1.z = (e1 + 2 < e_end) ? row[e1 + 2] : -1;
        r1.w = (e1 + 3 < e_end) ? row[e1 + 3] : -1;
        c1.x = (e1 + 0 < e_end) ? col[e1 + 0] : 0;
        c1.y = (e1 + 1 < e_end) ? col[e1 + 1] : 0;
        c1.z = (e1 + 2 < e_end) ? col[e1 + 2] : 0;
        c1.w = (e1 + 3 < e_end) ? col[e1 + 3] : 0;
    }
    __syncthreads();  // hist zeroed

    if (r0.x >= 0) atomicAdd(&hist[r0.x >> LOG_BN], 1);
    if (r0.y >= 0) atomicAdd(&hist[r0.y >> LOG_BN], 1);
    if (r0.z >= 0) atomicAdd(&hist[r0.z >> LOG_BN], 1);
    if (r0.w >= 0) atomicAdd(&hist[r0.w >> LOG_BN], 1);
    if (r1.x >= 0) atomicAdd(&hist[r1.x >> LOG_BN], 1);
    if (r1.y >= 0) atomicAdd(&hist[r1.y >> LOG_BN], 1);
    if (r1.z >= 0) atomicAdd(&hist[r1.z >> LOG_BN], 1);
    if (r1.w >= 0) atomicAdd(&hist[r1.w >> LOG_BN], 1);
    __syncthreads();

    // reserve fixed-capacity region slots: one global atomic per (chunk,bucket)
    for (int i = t; i < nb; i += BIG) {
        int h = hist[i];
        base[i] = h ? (i * CAP + atomicAdd(&cnt[i], h)) : 0;
    }
    __syncthreads();

    #define EMIT(rr, cc)                                                      \
        if ((rr) >= 0) {                                                      \
            int b_ = (rr) >> LOG_BN;                                          \
            int slot_ = base[b_] + atomicAdd(&hist[b_], -1) - 1;              \
            packed[slot_] = ((unsigned)((rr) & (BNODES - 1)) << 17) |         \
                            (unsigned)(cc);                                   \
        }
    EMIT(r0.x, c0.x); EMIT(r0.y, c0.y); EMIT(r0.z, c0.z); EMIT(r0.w, c0.w);
    EMIT(r1.x, c1.x); EMIT(r1.y, c1.y); EMIT(r1.z, c1.z); EMIT(r1.w, c1.w);
    #undef EMIT
}

// ---- phase 2: in-block counting sort + register-accumulated reduce ----
// 512 threads: thread t owns (node = t>>3 in 0..63, quad j = t&7).
__global__ void __launch_bounds__(512) phase2_kernel(const float* __restrict__ x,
                                                     const unsigned* __restrict__ packed,
                                                     const int* __restrict__ cnt,
                                                     float* __restrict__ out, int N) {
    __shared__ unsigned scol[ECHUNK];   // 8 KB: row-sorted packed entries
    __shared__ int hist[BNODES];
    __shared__ int hoff[BNODES];
    int t = threadIdx.x;
    int b = blockIdx.x;
    int s = b * CAP;
    int n = cnt[b];
    int node = t >> 3;
    int j = t & 7;
    const float4* x4 = (const float4*)x;

    float4 acc = make_float4(0.f, 0.f, 0.f, 0.f);
    int mydeg = 0;

    for (int cs = 0; cs < n; cs += ECHUNK) {
        int m = min(ECHUNK, n - cs);
        if (t < BNODES) hist[t] = 0;
        __syncthreads();
        for (int i = t; i < m; i += 512)
            atomicAdd(&hist[packed[s + cs + i] >> 17], 1);
        __syncthreads();
        // exclusive scan of 64 counters: one full wave shfl scan
        if (t < 64) {
            int v = hist[t];
            int sum = v;
            #pragma unroll
            for (int off = 1; off < 64; off <<= 1) {
                int w = __shfl_up(sum, off);
                if (t >= off) sum += w;
            }
            hoff[t] = sum - v;
        }
        __syncthreads();
        int mcount = hist[node];
        int mbase = hoff[node];
        mydeg += mcount;
        __syncthreads();
        for (int i = t; i < m; i += 512) {
            unsigned p = packed[s + cs + i];
            int r = p >> 17;
            int slot = hoff[r] + atomicAdd(&hist[r], -1) - 1;
            scol[slot] = p;
        }
        __syncthreads();

        // 8 independent float4 gathers in flight
        int i = 0;
        for (; i + 7 < mcount; i += 8) {
            unsigned cc0 = scol[mbase + i + 0] & CMASK;
            unsigned cc1 = scol[mbase + i + 1] & CMASK;
            unsigned cc2 = scol[mbase + i + 2] & CMASK;
            unsigned cc3 = scol[mbase + i + 3] & CMASK;
            unsigned cc4 = scol[mbase + i + 4] & CMASK;
            unsigned cc5 = scol[mbase + i + 5] & CMASK;
            unsigned cc6 = scol[mbase + i + 6] & CMASK;
            unsigned cc7 = scol[mbase + i + 7] & CMASK;
            float4 v0 = x4[cc0 * 8 + j];
            float4 v1 = x4[cc1 * 8 + j];
            float4 v2 = x4[cc2 * 8 + j];
            float4 v3 = x4[cc3 * 8 + j];
            float4 v4 = x4[cc4 * 8 + j];
            float4 v5 = x4[cc5 * 8 + j];
            float4 v6 = x4[cc6 * 8 + j];
            float4 v7 = x4[cc7 * 8 + j];
            acc.x += v0.x; acc.y += v0.y; acc.z += v0.z; acc.w += v0.w;
            acc.x += v1.x; acc.y += v1.y; acc.z += v1.z; acc.w += v1.w;
            acc.x += v2.x; acc.y += v2.y; acc.z += v2.z; acc.w += v2.w;
            acc.x += v3.x; acc.y += v3.y; acc.z += v3.z; acc.w += v3.w;
            acc.x += v4.x; acc.y += v4.y; acc.z += v4.z; acc.w += v4.w;
            acc.x += v5.x; acc.y += v5.y; acc.z += v5.z; acc.w += v5.w;
            acc.x += v6.x; acc.y += v6.y; acc.z += v6.z; acc.w += v6.w;
            acc.x += v7.x; acc.y += v7.y; acc.z += v7.z; acc.w += v7.w;
        }
        for (; i < mcount; ++i) {
            unsigned cc = scol[mbase + i] & CMASK;
            float4 v = x4[cc * 8 + j];
            acc.x += v.x; acc.y += v.y; acc.z += v.z; acc.w += v.w;
        }
        __syncthreads();
    }

    int gnode = b * BNODES + node;
    if (gnode < N) {
        float invd = 1.0f / fmaxf((float)mydeg, 1.0f);
        float4 v;
        v.x = acc.x * invd; v.y = acc.y * invd;
        v.z = acc.z * invd; v.w = acc.w * invd;
        ((float4*)out)[(size_t)gnode * 8 + j] = v;
    }
}

// ---------------- launch ----------------

extern "C" void kernel_launch(void* const* d_in, const int* in_sizes, int n_in,
                              void* d_out, int out_size, void* d_ws, size_t ws_size,
                              hipStream_t stream) {
    const float* x = (const float*)d_in[0];
    const int* edge_index = (const int*)d_in[1];

    int E = in_sizes[1] / 2;
    const int* row = edge_index;      // edge_index[0]
    const int* col = edge_index + E;  // edge_index[1]
    int N = in_sizes[0] / D_FEAT;

    float* out = (float*)d_out;

    int nb = (N + BNODES - 1) / BNODES;     // 1563 buckets
    int nchunks = (E + CHUNK - 1) / CHUNK;  // 196

    // ws layout (ints): cnt[nb] (64-aligned pad) | packed[nb*CAP]  (~12.8 MB)
    int* cnt = (int*)d_ws;
    unsigned* packed = (unsigned*)(cnt + ((nb + 63) & ~63));

    zero_kernel<<<(nb + 255) / 256, 256, 0, stream>>>(cnt, nb);

    size_t lds = (size_t)2 * nb * sizeof(int);
    build_kernel<<<nchunks, BIG, lds, stream>>>(row, col, cnt, packed, E, nb);
    phase2_kernel<<<nb, 512, 0, stream>>>(x, packed, cnt, out, N);
}